// Round 4
// baseline (283.627 us; speedup 1.0000x reference)
//
#include <hip/hip_runtime.h>

// Problem constants: x is (256, 3, 224, 224) float32.
#define N_IMG   256
#define HW      (224 * 224)        // 50176
#define CHW     (3 * HW)           // 150528 floats per image
#define V4      (CHW / 4)          // 37632 float4 per image
#define THREADS 256

// Single fused kernel: 7 chunks/image, 21 float4/thread in 3 groups of 7
#define CHUNKS      7
#define CHUNK_V4    (V4 / CHUNKS)          // 5376
#define PER_THREAD  (CHUNK_V4 / THREADS)   // 21
#define GROUPS      3
#define GSIZE       7                       // GROUPS*GSIZE == PER_THREAD

#define MAGS_PER_TF 9

// Native clang vector type — required for __builtin_nontemporal_store
typedef float fvec4 __attribute__((ext_vector_type(4)));

__device__ __forceinline__ float clip01(float v) {
    return fminf(fmaxf(v, 0.0f), 1.0f);
}

// Single fused kernel. Whole block works on one image -> every branch is
// wave-uniform. Contrast blocks (tf==1 && applied, ~1/8 of images) compute
// the full-image mean inline by streaming the image (602 KB, L2/L3-hot);
// all other blocks go straight to the transform.
__global__ __launch_bounds__(THREADS) void fused_kernel(
        const float* __restrict__ x,
        const int* __restrict__ sample,
        const int* __restrict__ apply_mask,
        float* __restrict__ out) {
    const int img   = blockIdx.y;
    const int chunk = blockIdx.x;
    const int s     = sample[img];
    const int tf    = s / MAGS_PER_TF;
    const float mag = (float)(s % MAGS_PER_TF + 1) * 0.1f;
    const bool applied = apply_mask[s] > 0;

    const fvec4* ximg = (const fvec4*)x + (size_t)img * V4;

    // ---- inline mean (contrast images only; block-uniform branch) ----
    float mean = 0.0f;
    if (applied && tf == 1) {
        float sum = 0.0f;
#pragma unroll 7
        for (int k = 0; k < V4 / THREADS; ++k) {     // 147 iterations
            fvec4 t = ximg[threadIdx.x + k * THREADS];
            sum += (t.x + t.y) + (t.z + t.w);
        }
        // 64-lane wave reduction
#pragma unroll
        for (int off = 32; off > 0; off >>= 1)
            sum += __shfl_down(sum, off, 64);
        __shared__ float wsum[THREADS / 64];
        if ((threadIdx.x & 63) == 0) wsum[threadIdx.x >> 6] = sum;
        __syncthreads();
        mean = ((wsum[0] + wsum[1]) + (wsum[2] + wsum[3])) * (1.0f / (float)CHW);
    }

    // ---- transform this block's chunk: 3 groups of 7 float4/thread ----
    const size_t base = (size_t)chunk * CHUNK_V4 + threadIdx.x;
    const fvec4* xp = ximg + base;
    fvec4*       op = (fvec4*)out + (size_t)img * V4 + base;

    const float g1 = 1.0f + mag;       // contrast / gain gain
    const float a2 = 1.0f - 2.0f * mag; // invert-lerp slope: a*x+mag*(1-x) = (1-2m)x + m

#pragma unroll
    for (int g = 0; g < GROUPS; ++g) {
        fvec4 v[GSIZE];
#pragma unroll
        for (int k = 0; k < GSIZE; ++k)
            v[k] = xp[(g * GSIZE + k) * THREADS];

        if (!applied) {
            // passthrough
        } else if (tf == 0) {          // brightness: clip(x + mag)
#pragma unroll
            for (int k = 0; k < GSIZE; ++k) {
                v[k].x = clip01(v[k].x + mag);
                v[k].y = clip01(v[k].y + mag);
                v[k].z = clip01(v[k].z + mag);
                v[k].w = clip01(v[k].w + mag);
            }
        } else if (tf == 1) {          // contrast: clip(mean + (x-mean)*(1+mag))
#pragma unroll
            for (int k = 0; k < GSIZE; ++k) {
                v[k].x = clip01(mean + (v[k].x - mean) * g1);
                v[k].y = clip01(mean + (v[k].y - mean) * g1);
                v[k].z = clip01(mean + (v[k].z - mean) * g1);
                v[k].w = clip01(mean + (v[k].w - mean) * g1);
            }
        } else if (tf == 2) {          // invert-lerp: (1-2m)*x + m, NO clip
#pragma unroll
            for (int k = 0; k < GSIZE; ++k) {
                v[k].x = a2 * v[k].x + mag;
                v[k].y = a2 * v[k].y + mag;
                v[k].z = a2 * v[k].z + mag;
                v[k].w = a2 * v[k].w + mag;
            }
        } else {                       // gain: clip(x * (1+mag))
#pragma unroll
            for (int k = 0; k < GSIZE; ++k) {
                v[k].x = clip01(v[k].x * g1);
                v[k].y = clip01(v[k].y * g1);
                v[k].z = clip01(v[k].z * g1);
                v[k].w = clip01(v[k].w * g1);
            }
        }

#pragma unroll
        for (int k = 0; k < GSIZE; ++k)
            __builtin_nontemporal_store(v[k], op + (g * GSIZE + k) * THREADS);
    }
}

extern "C" void kernel_launch(void* const* d_in, const int* in_sizes, int n_in,
                              void* d_out, int out_size, void* d_ws, size_t ws_size,
                              hipStream_t stream) {
    const float* x          = (const float*)d_in[0];
    const int*   sample     = (const int*)d_in[1];
    const int*   apply_mask = (const int*)d_in[2];
    float*       out        = (float*)d_out;

    dim3 grid(CHUNKS, N_IMG);
    fused_kernel<<<grid, THREADS, 0, stream>>>(x, sample, apply_mask, out);
}